// Round 1
// baseline (764.249 us; speedup 1.0000x reference)
//
#include <hip/hip_runtime.h>
#include <hip/hip_bf16.h>
#include <cstdint>

#define NLOC 128        // nodes per graph
#define NGRAPH 128      // bs*T
#define NNODE 16384     // total nodes
#define EBASE 2048      // base edges per graph
#define CSTRIDE 256     // csr col stride per local node

__device__ __forceinline__ float sigf(float x) { return 1.f / (1.f + __expf(-x)); }
__device__ __forceinline__ float tanhfast(float x) {
    float e = __expf(2.f * x);
    return 1.f - 2.f / (e + 1.f);
}
__device__ __forceinline__ uint32_t bf16r(float x) {
    uint32_t u = __float_as_uint(x);
    return (u + 0x7fffu + ((u >> 16) & 1u)) >> 16;
}
__device__ __forceinline__ uint32_t pack2(float a, float b) { return bf16r(a) | (bf16r(b) << 16); }
__device__ __forceinline__ float ubf_lo(uint32_t p) { return __uint_as_float(p << 16); }
__device__ __forceinline__ float ubf_hi(uint32_t p) { return __uint_as_float(p & 0xffff0000u); }

// ---------------- CSR of the shared per-graph edge list (dst -> list of src) ----------------
__global__ __launch_bounds__(1024) void build_csr_kernel(const int* __restrict__ ei,
                                                         int* __restrict__ cnt,
                                                         int* __restrict__ col,
                                                         int* __restrict__ flags) {
    __shared__ int c8[NLOC][8];
    int tid = threadIdx.x;
    int v = tid >> 3, p = tid & 7;
    const int* srcs = ei;
    const int* dsts = ei + EBASE;
    int e0 = p * 256, e1 = e0 + 256;
    int c = 0;
    for (int e = e0; e < e1; ++e) c += (dsts[e] == v);
    c8[v][p] = c;
    __syncthreads();
    int start = 0;
    for (int q = 0; q < p; ++q) start += c8[v][q];
    if (p == 0) {
        int tot = 0;
        for (int q = 0; q < 8; ++q) tot += c8[v][q];
        cnt[v] = tot;
    }
    int w = start;
    for (int e = e0; e < e1; ++e)
        if (dsts[e] == v) col[v * CSTRIDE + (w++)] = srcs[e];
    if (tid < 16) flags[tid] = 0;  // LSTM sync flags reset each launch
}

// ---------------- fp32 tiled GEMM: C[M,N] = A[M,K] @ B[K,N]; M%64==0, N%64==0, K%16==0 ----
__global__ __launch_bounds__(256) void gemm_kernel(const float* __restrict__ A,
                                                   const float* __restrict__ B,
                                                   float* __restrict__ C,
                                                   int M, int N, int K) {
    __shared__ __align__(16) float As[16][64];
    __shared__ __align__(16) float Bs[16][64];
    int tid = threadIdx.x;
    int bm = blockIdx.y, bn = blockIdx.x;
    int am = tid >> 2, ak = (tid & 3) << 2;
    int bk = tid >> 4, bn4 = (tid & 15) << 2;
    int ty = tid >> 4, tx = tid & 15;
    const float* Ab = A + (size_t)bm * 64 * K;
    const float* Bb = B + bn * 64;
    float acc[4][4] = {};
    for (int k0 = 0; k0 < K; k0 += 16) {
        float4 av = *(const float4*)(Ab + (size_t)am * K + k0 + ak);
        float4 bv = *(const float4*)(Bb + (size_t)(k0 + bk) * N + bn4);
        As[ak + 0][am] = av.x; As[ak + 1][am] = av.y;
        As[ak + 2][am] = av.z; As[ak + 3][am] = av.w;
        *(float4*)&Bs[bk][bn4] = bv;
        __syncthreads();
#pragma unroll
        for (int kk = 0; kk < 16; ++kk) {
            float4 a4 = *(const float4*)&As[kk][ty << 2];
            float4 b4 = *(const float4*)&Bs[kk][tx << 2];
            acc[0][0] += a4.x * b4.x; acc[0][1] += a4.x * b4.y; acc[0][2] += a4.x * b4.z; acc[0][3] += a4.x * b4.w;
            acc[1][0] += a4.y * b4.x; acc[1][1] += a4.y * b4.y; acc[1][2] += a4.y * b4.z; acc[1][3] += a4.y * b4.w;
            acc[2][0] += a4.z * b4.x; acc[2][1] += a4.z * b4.y; acc[2][2] += a4.z * b4.z; acc[2][3] += a4.z * b4.w;
            acc[3][0] += a4.w * b4.x; acc[3][1] += a4.w * b4.y; acc[3][2] += a4.w * b4.z; acc[3][3] += a4.w * b4.w;
        }
        __syncthreads();
    }
    float* Cb = C + (size_t)(bm * 64 + ty * 4) * N + bn * 64 + tx * 4;
#pragma unroll
    for (int i = 0; i < 4; ++i)
        *(float4*)(Cb + (size_t)i * N) = make_float4(acc[i][0], acc[i][1], acc[i][2], acc[i][3]);
}

// ---------------- attention dot products per node ----------------
template <int H>
__global__ __launch_bounds__(256) void att_kernel(const float* __restrict__ hf,
                                                  const float* __restrict__ a_s,
                                                  const float* __restrict__ a_d,
                                                  float* __restrict__ asb,
                                                  float* __restrict__ adb) {
    int lane = threadIdx.x & 63;
    int n = blockIdx.x * 4 + (threadIdx.x >> 6);
    const float* row = hf + (size_t)n * (H * 64);
#pragma unroll
    for (int h = 0; h < H; ++h) {
        float v = row[h * 64 + lane];
        float ps = v * a_s[h * 64 + lane];
        float pd = v * a_d[h * 64 + lane];
#pragma unroll
        for (int off = 32; off > 0; off >>= 1) {
            ps += __shfl_xor(ps, off, 64);
            pd += __shfl_xor(pd, off, 64);
        }
        if (lane == 0) { asb[n * H + h] = ps; adb[n * H + h] = pd; }
    }
}

// ---------------- GAT aggregation: softmax over in-edges, gather, +bias, ReLU -------------
template <int H>
__global__ __launch_bounds__(256) void agg_kernel(const float* __restrict__ hf,
                                                  const float* __restrict__ asb,
                                                  const float* __restrict__ adb,
                                                  const int* __restrict__ cnt,
                                                  const int* __restrict__ col,
                                                  const float* __restrict__ bias,
                                                  float* __restrict__ out) {
    __shared__ float e_lds[4][96][H];
    __shared__ int u_lds[4][96];
    int lane = threadIdx.x & 63, w = threadIdx.x >> 6;
    int n = blockIdx.x * 4 + w;
    int v = n & 127, base = n & ~127;
    int deg = cnt[v];
    int tot = min(deg + 1, 96);
    float adst[H];
#pragma unroll
    for (int h = 0; h < H; ++h) adst[h] = adb[n * H + h];
    for (int k = lane; k < tot; k += 64) {
        int u = (k < deg) ? col[v * CSTRIDE + k] : v;
        u_lds[w][k] = u;
#pragma unroll
        for (int h = 0; h < H; ++h) {
            float e = asb[(base + u) * H + h] + adst[h];
            e_lds[w][k][h] = (e > 0.f) ? e : 0.2f * e;
        }
    }
    __syncthreads();
    float m[H];
#pragma unroll
    for (int h = 0; h < H; ++h) m[h] = -1e30f;
    for (int k = 0; k < tot; ++k)
#pragma unroll
        for (int h = 0; h < H; ++h) m[h] = fmaxf(m[h], e_lds[w][k][h]);
    __syncthreads();
    for (int k = lane; k < tot; k += 64)
#pragma unroll
        for (int h = 0; h < H; ++h) e_lds[w][k][h] = __expf(e_lds[w][k][h] - m[h]);
    __syncthreads();
    float den[H], acc[H];
#pragma unroll
    for (int h = 0; h < H; ++h) { den[h] = 0.f; acc[h] = 0.f; }
    for (int k = 0; k < tot; ++k) {
        int u = u_lds[w][k];
        const float* hr = hf + (size_t)(base + u) * (H * 64);
#pragma unroll
        for (int h = 0; h < H; ++h) {
            float wgt = e_lds[w][k][h];
            den[h] += wgt;
            acc[h] += wgt * hr[h * 64 + lane];
        }
    }
#pragma unroll
    for (int h = 0; h < H; ++h) {
        float o = acc[h] / (den[h] + 1e-16f) + bias[h * 64 + lane];
        out[(size_t)n * (H * 64) + h * 64 + lane] = fmaxf(o, 0.f);
    }
}

// ---------------- graph sum-pool into sequence layout [t*4+b][64] ----------------
__global__ void pool_kernel(const float* __restrict__ h, float* __restrict__ gemb) {
    int g = blockIdx.x;       // g = b*32 + t
    int c = threadIdx.x;      // 64 threads
    int b = g >> 5, t = g & 31;
    float s = 0.f;
    const float* p = h + (size_t)g * 128 * 64 + c;
    for (int vv = 0; vv < 128; ++vv) s += p[vv * 64];
    gemb[(t * 4 + b) * 64 + c] = s;
}

// ---------------- LSTM input part: xp[dir][r][o] = seq[r] . Wih[o] + bih[o] + bhh[o] ------
__global__ __launch_bounds__(256) void xpart_kernel(const float* __restrict__ gemb,
                                                    const float* __restrict__ Wf, const float* __restrict__ bif, const float* __restrict__ bhf,
                                                    const float* __restrict__ Wb, const float* __restrict__ bib, const float* __restrict__ bhb,
                                                    float* __restrict__ xp) {
    __shared__ float a[64];
    int r = blockIdx.x, tid = threadIdx.x;
    if (tid < 64) a[tid] = gemb[r * 64 + tid];
    __syncthreads();
    for (int dir = 0; dir < 2; ++dir) {
        const float* W = dir ? Wb : Wf;
        const float* bi = dir ? bib : bif;
        const float* bh = dir ? bhb : bhf;
        for (int o = tid; o < 1024; o += 256) {
            const float* wr = W + (size_t)o * 64;
            float s = bi[o] + bh[o];
#pragma unroll
            for (int k = 0; k < 64; k += 4) {
                float4 wv = *(const float4*)(wr + k);
                s += a[k] * wv.x + a[k + 1] * wv.y + a[k + 2] * wv.z + a[k + 3] * wv.w;
            }
            xp[dir * 131072 + r * 1024 + o] = s;
        }
    }
}

// ---------------- BiLSTM recurrent: 8 blocks (4 per dir), flag-sync per step --------------
__global__ __launch_bounds__(512) void lstm_kernel(const float* __restrict__ xp,
                                                   const float* __restrict__ Whh_f,
                                                   const float* __restrict__ Whh_b,
                                                   float* __restrict__ hhist,
                                                   int* flags) {
    int wg = blockIdx.x;
    int dir = wg >> 2, q = wg & 3;
    const float* Whh = dir ? Whh_b : Whh_f;
    int tid = threadIdx.x;
    int lr = tid & 255, ch = tid >> 8;          // lr = gate*64+jloc; ch = column half
    int gate = lr >> 6, jloc = lr & 63;
    int grow = gate * 256 + q * 64 + jloc;
    uint32_t wpk[64];
    const float* wr = Whh + (size_t)grow * 256 + ch * 128;
#pragma unroll
    for (int i = 0; i < 32; ++i) {
        float4 wv = *(const float4*)(wr + i * 4);
        wpk[2 * i] = pack2(wv.x, wv.y);
        wpk[2 * i + 1] = pack2(wv.z, wv.w);
    }
    __shared__ __align__(16) float h_lds[256][4];
    __shared__ __align__(16) float part[2][256][4];
    __shared__ __align__(16) float gbuf[4][64][4];
    float creg = 0.f;
    int cj = tid & 63, cb = (tid >> 6) & 3;     // c/h owner mapping (tid<256)
    for (int step = 0; step < 32; ++step) {
        if (step > 0) {
            if (tid < 4 && tid != q) {
                while (__hip_atomic_load(&flags[dir * 4 + tid], __ATOMIC_ACQUIRE,
                                         __HIP_MEMORY_SCOPE_AGENT) < step)
                    __builtin_amdgcn_s_sleep(1);
            }
            __syncthreads();
            const float* hs = hhist + (size_t)((dir * 32 + step - 1) * 4) * 256;
            for (int i = tid; i < 1024; i += 512) h_lds[i & 255][i >> 8] = hs[i];
        } else {
            for (int i = tid; i < 1024; i += 512) h_lds[i & 255][i >> 8] = 0.f;
        }
        __syncthreads();
        float a0 = 0.f, a1 = 0.f, a2 = 0.f, a3 = 0.f;
        int cbase = ch * 128;
#pragma unroll
        for (int cc = 0; cc < 32; ++cc) {
            int c = cbase + cc * 4;
            float4 hA = *(const float4*)&h_lds[c][0];
            float4 hB = *(const float4*)&h_lds[c + 1][0];
            float4 hC = *(const float4*)&h_lds[c + 2][0];
            float4 hD = *(const float4*)&h_lds[c + 3][0];
            uint32_t p0 = wpk[2 * cc], p1 = wpk[2 * cc + 1];
            float w0 = ubf_lo(p0), w1 = ubf_hi(p0), w2 = ubf_lo(p1), w3 = ubf_hi(p1);
            a0 += w0 * hA.x + w1 * hB.x + w2 * hC.x + w3 * hD.x;
            a1 += w0 * hA.y + w1 * hB.y + w2 * hC.y + w3 * hD.y;
            a2 += w0 * hA.z + w1 * hB.z + w2 * hC.z + w3 * hD.z;
            a3 += w0 * hA.w + w1 * hB.w + w2 * hC.w + w3 * hD.w;
        }
        *(float4*)&part[ch][lr][0] = make_float4(a0, a1, a2, a3);
        __syncthreads();
        if (tid < 256) {
            int g2 = tid >> 6, j2 = tid & 63;
            int gr2 = g2 * 256 + q * 64 + j2;
            int teff = dir ? (31 - step) : step;
            const float* x0 = xp + dir * 131072 + (size_t)teff * 4096 + gr2;
            float4 p0 = *(const float4*)&part[0][tid][0];
            float4 p1 = *(const float4*)&part[1][tid][0];
            gbuf[g2][j2][0] = x0[0] + p0.x + p1.x;
            gbuf[g2][j2][1] = x0[1024] + p0.y + p1.y;
            gbuf[g2][j2][2] = x0[2048] + p0.z + p1.z;
            gbuf[g2][j2][3] = x0[3072] + p0.w + p1.w;
        }
        __syncthreads();
        if (tid < 256) {
            float iv = gbuf[0][cj][cb], fv = gbuf[1][cj][cb];
            float gv = gbuf[2][cj][cb], ov = gbuf[3][cj][cb];
            creg = sigf(fv) * creg + sigf(iv) * tanhfast(gv);
            float hv = sigf(ov) * tanhfast(creg);
            hhist[(size_t)((dir * 32 + step) * 4 + cb) * 256 + q * 64 + cj] = hv;
            __threadfence();
        }
        __syncthreads();
        if (tid == 0)
            __hip_atomic_store(&flags[dir * 4 + q], step + 1, __ATOMIC_RELEASE,
                               __HIP_MEMORY_SCOPE_AGENT);
    }
}

// ---------------- heads: mu/logvar/pi from concat(h_f, h_b) ----------------
__global__ __launch_bounds__(256) void heads_kernel(const float* __restrict__ hhist,
                                                    const float* __restrict__ Wmu, const float* __restrict__ bmu,
                                                    const float* __restrict__ Wlv, const float* __restrict__ blv,
                                                    const float* __restrict__ Wpi, const float* __restrict__ bpi,
                                                    float* __restrict__ out) {
    __shared__ __align__(16) float feat[4][512];
    int tid = threadIdx.x;
    for (int i = tid; i < 2048; i += 256) {
        int b = i >> 9, j = i & 511;
        int d = j >> 8, jj = j & 255;
        feat[b][j] = hhist[(size_t)((d * 32 + 31) * 4 + b) * 256 + jj];
    }
    __syncthreads();
    int o = blockIdx.x * 256 + tid;
    if (o >= 4128) return;
    const float* Wr;
    float bv;
    int kind, m;
    if (o < 2048) { Wr = Wmu + (size_t)o * 512; bv = bmu[o]; kind = 0; m = o; }
    else if (o < 4096) { m = o - 2048; Wr = Wlv + (size_t)m * 512; bv = blv[m]; kind = 1; }
    else { m = o - 4096; Wr = Wpi + (size_t)m * 512; bv = bpi[m]; kind = 2; }
    float s0 = bv, s1 = bv, s2 = bv, s3 = bv;
    for (int k = 0; k < 512; k += 4) {
        float4 wv = *(const float4*)(Wr + k);
        s0 += feat[0][k] * wv.x + feat[0][k + 1] * wv.y + feat[0][k + 2] * wv.z + feat[0][k + 3] * wv.w;
        s1 += feat[1][k] * wv.x + feat[1][k + 1] * wv.y + feat[1][k + 2] * wv.z + feat[1][k + 3] * wv.w;
        s2 += feat[2][k] * wv.x + feat[2][k + 1] * wv.y + feat[2][k + 2] * wv.z + feat[2][k + 3] * wv.w;
        s3 += feat[3][k] * wv.x + feat[3][k + 1] * wv.y + feat[3][k + 2] * wv.z + feat[3][k + 3] * wv.w;
    }
    if (kind == 0) {
        out[0 * 2048 + m] = s0; out[1 * 2048 + m] = s1; out[2 * 2048 + m] = s2; out[3 * 2048 + m] = s3;
    } else if (kind == 1) {
        out[8192 + 0 * 2048 + m] = s0; out[8192 + 1 * 2048 + m] = s1;
        out[8192 + 2 * 2048 + m] = s2; out[8192 + 3 * 2048 + m] = s3;
    } else {
        out[16384 + 0 * 32 + m] = s0; out[16384 + 1 * 32 + m] = s1;
        out[16384 + 2 * 32 + m] = s2; out[16384 + 3 * 32 + m] = s3;
    }
}

extern "C" void kernel_launch(void* const* d_in, const int* in_sizes, int n_in,
                              void* d_out, int out_size, void* d_ws, size_t ws_size,
                              hipStream_t stream) {
    const float* x = (const float*)d_in[0];
    const int* ei = (const int*)d_in[1];
    const float* W1 = (const float*)d_in[2];
    const float* as1 = (const float*)d_in[3];
    const float* ad1 = (const float*)d_in[4];
    const float* b1 = (const float*)d_in[5];
    const float* W2 = (const float*)d_in[6];
    const float* as2 = (const float*)d_in[7];
    const float* ad2 = (const float*)d_in[8];
    const float* b2 = (const float*)d_in[9];
    const float* W3 = (const float*)d_in[10];
    const float* as3 = (const float*)d_in[11];
    const float* ad3 = (const float*)d_in[12];
    const float* b3 = (const float*)d_in[13];
    const float* Wih_f = (const float*)d_in[14];
    const float* Whh_f = (const float*)d_in[15];
    const float* bih_f = (const float*)d_in[16];
    const float* bhh_f = (const float*)d_in[17];
    const float* Wih_b = (const float*)d_in[18];
    const float* Whh_b = (const float*)d_in[19];
    const float* bih_b = (const float*)d_in[20];
    const float* bhh_b = (const float*)d_in[21];
    const float* Wmu = (const float*)d_in[22];
    const float* bmu = (const float*)d_in[23];
    const float* Wlv = (const float*)d_in[24];
    const float* blv = (const float*)d_in[25];
    const float* Wpi = (const float*)d_in[26];
    const float* bpi = (const float*)d_in[27];

    float* ws = (float*)d_ws;
    float* bufA = ws;                    // 4,194,304 f32 (feature buffer)
    float* bufB = ws + 4194304;          // 4,194,304 f32 (output buffer)
    float* asb = ws + 8388608;           // 65,536
    float* adb = ws + 8454144;           // 65,536
    int* cnt = (int*)(ws + 8519680);     // 128 ints
    int* col = cnt + 128;                // 32,768 ints
    float* gemb = ws + 8552576;          // 8,192
    float* xp = ws + 8560768;            // 262,144
    float* hh = ws + 8822912;            // 65,536
    int* flags = (int*)(ws + 8888448);   // 16 ints
    float* out = (float*)d_out;

    build_csr_kernel<<<1, 1024, 0, stream>>>(ei, cnt, col, flags);

    // GAT layer 1
    gemm_kernel<<<dim3(4, 256), 256, 0, stream>>>(x, W1, bufA, NNODE, 256, 64);
    att_kernel<4><<<4096, 256, 0, stream>>>(bufA, as1, ad1, asb, adb);
    agg_kernel<4><<<4096, 256, 0, stream>>>(bufA, asb, adb, cnt, col, b1, bufB);
    // GAT layer 2
    gemm_kernel<<<dim3(4, 256), 256, 0, stream>>>(bufB, W2, bufA, NNODE, 256, 256);
    att_kernel<4><<<4096, 256, 0, stream>>>(bufA, as2, ad2, asb, adb);
    agg_kernel<4><<<4096, 256, 0, stream>>>(bufA, asb, adb, cnt, col, b2, bufB);
    // GAT layer 3 (single head)
    gemm_kernel<<<dim3(1, 256), 256, 0, stream>>>(bufB, W3, bufA, NNODE, 64, 256);
    att_kernel<1><<<4096, 256, 0, stream>>>(bufA, as3, ad3, asb, adb);
    agg_kernel<1><<<4096, 256, 0, stream>>>(bufA, asb, adb, cnt, col, b3, bufB);
    // pool + BiLSTM + heads
    pool_kernel<<<128, 64, 0, stream>>>(bufB, gemb);
    xpart_kernel<<<128, 256, 0, stream>>>(gemb, Wih_f, bih_f, bhh_f, Wih_b, bih_b, bhh_b, xp);
    lstm_kernel<<<8, 512, 0, stream>>>(xp, Whh_f, Whh_b, hh, flags);
    heads_kernel<<<17, 256, 0, stream>>>(hh, Wmu, bmu, Wlv, blv, Wpi, bpi, out);
}

// Round 2
// 698.924 us; speedup vs baseline: 1.0935x; 1.0935x over previous
//
#include <hip/hip_runtime.h>
#include <hip/hip_bf16.h>
#include <cstdint>

#define NLOC 128        // nodes per graph
#define NGRAPH 128      // bs*T
#define NNODE 16384     // total nodes
#define EBASE 2048      // base edges per graph
#define CSTRIDE 256     // csr col stride per local node

__device__ __forceinline__ float sigf(float x) { return 1.f / (1.f + __expf(-x)); }
__device__ __forceinline__ float tanhfast(float x) {
    float e = __expf(2.f * x);
    return 1.f - 2.f / (e + 1.f);
}
__device__ __forceinline__ uint32_t bf16r(float x) {
    uint32_t u = __float_as_uint(x);
    return (u + 0x7fffu + ((u >> 16) & 1u)) >> 16;
}
__device__ __forceinline__ uint32_t pack2(float a, float b) { return bf16r(a) | (bf16r(b) << 16); }
__device__ __forceinline__ float ubf_lo(uint32_t p) { return __uint_as_float(p << 16); }
__device__ __forceinline__ float ubf_hi(uint32_t p) { return __uint_as_float(p & 0xffff0000u); }

// ---------------- CSR of the shared per-graph edge list (dst -> list of src) ----------------
__global__ __launch_bounds__(1024) void build_csr_kernel(const int* __restrict__ ei,
                                                         int* __restrict__ cnt,
                                                         int* __restrict__ col) {
    __shared__ int c8[NLOC][8];
    int tid = threadIdx.x;
    int v = tid >> 3, p = tid & 7;
    const int* srcs = ei;
    const int* dsts = ei + EBASE;
    int e0 = p * 256, e1 = e0 + 256;
    int c = 0;
    for (int e = e0; e < e1; ++e) c += (dsts[e] == v);
    c8[v][p] = c;
    __syncthreads();
    int start = 0;
    for (int q = 0; q < p; ++q) start += c8[v][q];
    if (p == 0) {
        int tot = 0;
        for (int q = 0; q < 8; ++q) tot += c8[v][q];
        cnt[v] = tot;
    }
    int w = start;
    for (int e = e0; e < e1; ++e)
        if (dsts[e] == v) col[v * CSTRIDE + (w++)] = srcs[e];
}

// ---------------- fp32 tiled GEMM: C[M,N] = A[M,K] @ B[K,N]; M%64==0, N%64==0, K%16==0 ----
__global__ __launch_bounds__(256) void gemm_kernel(const float* __restrict__ A,
                                                   const float* __restrict__ B,
                                                   float* __restrict__ C,
                                                   int M, int N, int K) {
    __shared__ __align__(16) float As[16][64];
    __shared__ __align__(16) float Bs[16][64];
    int tid = threadIdx.x;
    int bm = blockIdx.y, bn = blockIdx.x;
    int am = tid >> 2, ak = (tid & 3) << 2;
    int bk = tid >> 4, bn4 = (tid & 15) << 2;
    int ty = tid >> 4, tx = tid & 15;
    const float* Ab = A + (size_t)bm * 64 * K;
    const float* Bb = B + bn * 64;
    float acc[4][4] = {};
    for (int k0 = 0; k0 < K; k0 += 16) {
        float4 av = *(const float4*)(Ab + (size_t)am * K + k0 + ak);
        float4 bv = *(const float4*)(Bb + (size_t)(k0 + bk) * N + bn4);
        As[ak + 0][am] = av.x; As[ak + 1][am] = av.y;
        As[ak + 2][am] = av.z; As[ak + 3][am] = av.w;
        *(float4*)&Bs[bk][bn4] = bv;
        __syncthreads();
#pragma unroll
        for (int kk = 0; kk < 16; ++kk) {
            float4 a4 = *(const float4*)&As[kk][ty << 2];
            float4 b4 = *(const float4*)&Bs[kk][tx << 2];
            acc[0][0] += a4.x * b4.x; acc[0][1] += a4.x * b4.y; acc[0][2] += a4.x * b4.z; acc[0][3] += a4.x * b4.w;
            acc[1][0] += a4.y * b4.x; acc[1][1] += a4.y * b4.y; acc[1][2] += a4.y * b4.z; acc[1][3] += a4.y * b4.w;
            acc[2][0] += a4.z * b4.x; acc[2][1] += a4.z * b4.y; acc[2][2] += a4.z * b4.z; acc[2][3] += a4.z * b4.w;
            acc[3][0] += a4.w * b4.x; acc[3][1] += a4.w * b4.y; acc[3][2] += a4.w * b4.z; acc[3][3] += a4.w * b4.w;
        }
        __syncthreads();
    }
    float* Cb = C + (size_t)(bm * 64 + ty * 4) * N + bn * 64 + tx * 4;
#pragma unroll
    for (int i = 0; i < 4; ++i)
        *(float4*)(Cb + (size_t)i * N) = make_float4(acc[i][0], acc[i][1], acc[i][2], acc[i][3]);
}

// ---------------- attention dot products per node ----------------
template <int H>
__global__ __launch_bounds__(256) void att_kernel(const float* __restrict__ hf,
                                                  const float* __restrict__ a_s,
                                                  const float* __restrict__ a_d,
                                                  float* __restrict__ asb,
                                                  float* __restrict__ adb) {
    int lane = threadIdx.x & 63;
    int n = blockIdx.x * 4 + (threadIdx.x >> 6);
    const float* row = hf + (size_t)n * (H * 64);
#pragma unroll
    for (int h = 0; h < H; ++h) {
        float v = row[h * 64 + lane];
        float ps = v * a_s[h * 64 + lane];
        float pd = v * a_d[h * 64 + lane];
#pragma unroll
        for (int off = 32; off > 0; off >>= 1) {
            ps += __shfl_xor(ps, off, 64);
            pd += __shfl_xor(pd, off, 64);
        }
        if (lane == 0) { asb[n * H + h] = ps; adb[n * H + h] = pd; }
    }
}

// ---------------- GAT aggregation: softmax over in-edges, gather, +bias, ReLU -------------
template <int H>
__global__ __launch_bounds__(256) void agg_kernel(const float* __restrict__ hf,
                                                  const float* __restrict__ asb,
                                                  const float* __restrict__ adb,
                                                  const int* __restrict__ cnt,
                                                  const int* __restrict__ col,
                                                  const float* __restrict__ bias,
                                                  float* __restrict__ out) {
    __shared__ float e_lds[4][96][H];
    __shared__ int u_lds[4][96];
    int lane = threadIdx.x & 63, w = threadIdx.x >> 6;
    int n = blockIdx.x * 4 + w;
    int v = n & 127, base = n & ~127;
    int deg = cnt[v];
    int tot = min(deg + 1, 96);
    float adst[H];
#pragma unroll
    for (int h = 0; h < H; ++h) adst[h] = adb[n * H + h];
    for (int k = lane; k < tot; k += 64) {
        int u = (k < deg) ? col[v * CSTRIDE + k] : v;
        u_lds[w][k] = u;
#pragma unroll
        for (int h = 0; h < H; ++h) {
            float e = asb[(base + u) * H + h] + adst[h];
            e_lds[w][k][h] = (e > 0.f) ? e : 0.2f * e;
        }
    }
    __syncthreads();
    float m[H];
#pragma unroll
    for (int h = 0; h < H; ++h) m[h] = -1e30f;
    for (int k = 0; k < tot; ++k)
#pragma unroll
        for (int h = 0; h < H; ++h) m[h] = fmaxf(m[h], e_lds[w][k][h]);
    __syncthreads();
    for (int k = lane; k < tot; k += 64)
#pragma unroll
        for (int h = 0; h < H; ++h) e_lds[w][k][h] = __expf(e_lds[w][k][h] - m[h]);
    __syncthreads();
    float den[H], acc[H];
#pragma unroll
    for (int h = 0; h < H; ++h) { den[h] = 0.f; acc[h] = 0.f; }
    for (int k = 0; k < tot; ++k) {
        int u = u_lds[w][k];
        const float* hr = hf + (size_t)(base + u) * (H * 64);
#pragma unroll
        for (int h = 0; h < H; ++h) {
            float wgt = e_lds[w][k][h];
            den[h] += wgt;
            acc[h] += wgt * hr[h * 64 + lane];
        }
    }
#pragma unroll
    for (int h = 0; h < H; ++h) {
        float o = acc[h] / (den[h] + 1e-16f) + bias[h * 64 + lane];
        out[(size_t)n * (H * 64) + h * 64 + lane] = fmaxf(o, 0.f);
    }
}

// ---------------- graph sum-pool into sequence layout [t*4+b][64] ----------------
__global__ void pool_kernel(const float* __restrict__ h, float* __restrict__ gemb) {
    int g = blockIdx.x;       // g = b*32 + t
    int c = threadIdx.x;      // 64 threads
    int b = g >> 5, t = g & 31;
    float s = 0.f;
    const float* p = h + (size_t)g * 128 * 64 + c;
    for (int vv = 0; vv < 128; ++vv) s += p[vv * 64];
    gemb[(t * 4 + b) * 64 + c] = s;
}

// ---------------- LSTM input part: xp[dir][r][o] = seq[r] . Wih[o] + bih[o] + bhh[o] ------
__global__ __launch_bounds__(256) void xpart_kernel(const float* __restrict__ gemb,
                                                    const float* __restrict__ Wf, const float* __restrict__ bif, const float* __restrict__ bhf,
                                                    const float* __restrict__ Wb, const float* __restrict__ bib, const float* __restrict__ bhb,
                                                    float* __restrict__ xp) {
    __shared__ float a[64];
    int r = blockIdx.x, tid = threadIdx.x;
    if (tid < 64) a[tid] = gemb[r * 64 + tid];
    __syncthreads();
    for (int dir = 0; dir < 2; ++dir) {
        const float* W = dir ? Wb : Wf;
        const float* bi = dir ? bib : bif;
        const float* bh = dir ? bhb : bhf;
        for (int o = tid; o < 1024; o += 256) {
            const float* wr = W + (size_t)o * 64;
            float s = bi[o] + bh[o];
#pragma unroll
            for (int k = 0; k < 64; k += 4) {
                float4 wv = *(const float4*)(wr + k);
                s += a[k] * wv.x + a[k + 1] * wv.y + a[k + 2] * wv.z + a[k + 3] * wv.w;
            }
            xp[dir * 131072 + r * 1024 + o] = s;
        }
    }
}

// ---------------- pre-pack + pre-swizzle Whh cols 192..255 (bf16 pairs) into ws -----------
__global__ __launch_bounds__(256) void wpack_kernel(const float* __restrict__ Whh_f,
                                                    const float* __restrict__ Whh_b,
                                                    uint32_t* __restrict__ wg) {
    int gid = blockIdx.x * 256 + threadIdx.x;   // 0..2047
    int dir = gid >> 10, row = gid & 1023;
    const float* src = (dir ? Whh_b : Whh_f) + (size_t)row * 256 + 192;
    uint32_t* dstrow = wg + (size_t)dir * 32768 + row * 32;
    int rx = row & 7;
#pragma unroll
    for (int s = 0; s < 8; ++s) {
#pragma unroll
        for (int kk = 0; kk < 4; ++kk) {
            float a = src[s * 8 + kk * 2], b = src[s * 8 + kk * 2 + 1];
            dstrow[(s ^ rx) * 4 + kk] = pack2(a, b);
        }
    }
}

// ---------------- BiLSTM recurrent: 8 independent blocks (dir x batch), no global sync ----
__global__ __launch_bounds__(1024, 1) void lstm_kernel(const float* __restrict__ xp,
                                                       const float* __restrict__ Whh_f,
                                                       const float* __restrict__ Whh_b,
                                                       const uint32_t* __restrict__ wg,
                                                       float* __restrict__ hT) {
    int blk = blockIdx.x;
    int dir = blk >> 2, batch = blk & 3;
    int o = threadIdx.x;                      // gate row 0..1023 (i,f,g,o x 256)
    const float* Whh = dir ? Whh_b : Whh_f;
    // cols 0..191 bf16-packed in 96 VGPRs
    uint32_t wpk[96];
    const float* wr = Whh + (size_t)o * 256;
#pragma unroll
    for (int g = 0; g < 48; ++g) {
        float4 wv = *(const float4*)(wr + g * 4);
        wpk[2 * g] = pack2(wv.x, wv.y);
        wpk[2 * g + 1] = pack2(wv.z, wv.w);
    }
    __shared__ uint32_t wlds[1024 * 32];      // 128 KB: cols 192..255, pre-swizzled
    __shared__ float h_lds[256];
    __shared__ float gv[1024];
    {
        const uint32_t* wsrc = wg + (size_t)dir * 32768;
        for (int k = 0; k < 32; ++k) wlds[o + k * 1024] = wsrc[o + k * 1024];
    }
    if (o < 256) h_lds[o] = 0.f;
    __syncthreads();
    float creg = 0.f;
    int rx = o & 7;
    const float* xpd = xp + dir * 131072 + batch * 1024 + o;
#pragma unroll 1
    for (int step = 0; step < 32; ++step) {
        int teff = dir ? (31 - step) : step;
        float xb = xpd[teff * 4096];
        float acc = 0.f;
#pragma unroll
        for (int q = 0; q < 24; ++q) {
            float4 hA = *(const float4*)&h_lds[q * 8];
            float4 hB = *(const float4*)&h_lds[q * 8 + 4];
            uint32_t p0 = wpk[q * 4], p1 = wpk[q * 4 + 1], p2 = wpk[q * 4 + 2], p3 = wpk[q * 4 + 3];
            acc += ubf_lo(p0) * hA.x + ubf_hi(p0) * hA.y + ubf_lo(p1) * hA.z + ubf_hi(p1) * hA.w;
            acc += ubf_lo(p2) * hB.x + ubf_hi(p2) * hB.y + ubf_lo(p3) * hB.z + ubf_hi(p3) * hB.w;
        }
#pragma unroll
        for (int s = 0; s < 8; ++s) {
            int p = s ^ rx;
            uint4 wq = *(const uint4*)&wlds[o * 32 + p * 4];
            float4 hA = *(const float4*)&h_lds[192 + s * 8];
            float4 hB = *(const float4*)&h_lds[192 + s * 8 + 4];
            acc += ubf_lo(wq.x) * hA.x + ubf_hi(wq.x) * hA.y + ubf_lo(wq.y) * hA.z + ubf_hi(wq.y) * hA.w;
            acc += ubf_lo(wq.z) * hB.x + ubf_hi(wq.z) * hB.y + ubf_lo(wq.w) * hB.z + ubf_hi(wq.w) * hB.w;
        }
        gv[o] = acc + xb;
        __syncthreads();
        if (o < 256) {
            float iv = gv[o], fv = gv[o + 256], gg = gv[o + 512], ov = gv[o + 768];
            creg = sigf(fv) * creg + sigf(iv) * tanhfast(gg);
            float hv = sigf(ov) * tanhfast(creg);
            h_lds[o] = hv;
            if (step == 31) hT[(size_t)(dir * 4 + batch) * 256 + o] = hv;
        }
        __syncthreads();
    }
}

// ---------------- heads: mu/logvar/pi from concat(h_f, h_b) ----------------
__global__ __launch_bounds__(256) void heads_kernel(const float* __restrict__ hT,
                                                    const float* __restrict__ Wmu, const float* __restrict__ bmu,
                                                    const float* __restrict__ Wlv, const float* __restrict__ blv,
                                                    const float* __restrict__ Wpi, const float* __restrict__ bpi,
                                                    float* __restrict__ out) {
    __shared__ __align__(16) float feat[4][512];
    int tid = threadIdx.x;
    for (int i = tid; i < 2048; i += 256) {
        int b = i >> 9, j = i & 511;
        int d = j >> 8, jj = j & 255;
        feat[b][j] = hT[(size_t)(d * 4 + b) * 256 + jj];
    }
    __syncthreads();
    int o = blockIdx.x * 256 + tid;
    if (o >= 4128) return;
    const float* Wr;
    float bv;
    int kind, m;
    if (o < 2048) { Wr = Wmu + (size_t)o * 512; bv = bmu[o]; kind = 0; m = o; }
    else if (o < 4096) { m = o - 2048; Wr = Wlv + (size_t)m * 512; bv = blv[m]; kind = 1; }
    else { m = o - 4096; Wr = Wpi + (size_t)m * 512; bv = bpi[m]; kind = 2; }
    float s0 = bv, s1 = bv, s2 = bv, s3 = bv;
    for (int k = 0; k < 512; k += 4) {
        float4 wv = *(const float4*)(Wr + k);
        s0 += feat[0][k] * wv.x + feat[0][k + 1] * wv.y + feat[0][k + 2] * wv.z + feat[0][k + 3] * wv.w;
        s1 += feat[1][k] * wv.x + feat[1][k + 1] * wv.y + feat[1][k + 2] * wv.z + feat[1][k + 3] * wv.w;
        s2 += feat[2][k] * wv.x + feat[2][k + 1] * wv.y + feat[2][k + 2] * wv.z + feat[2][k + 3] * wv.w;
        s3 += feat[3][k] * wv.x + feat[3][k + 1] * wv.y + feat[3][k + 2] * wv.z + feat[3][k + 3] * wv.w;
    }
    if (kind == 0) {
        out[0 * 2048 + m] = s0; out[1 * 2048 + m] = s1; out[2 * 2048 + m] = s2; out[3 * 2048 + m] = s3;
    } else if (kind == 1) {
        out[8192 + 0 * 2048 + m] = s0; out[8192 + 1 * 2048 + m] = s1;
        out[8192 + 2 * 2048 + m] = s2; out[8192 + 3 * 2048 + m] = s3;
    } else {
        out[16384 + 0 * 32 + m] = s0; out[16384 + 1 * 32 + m] = s1;
        out[16384 + 2 * 32 + m] = s2; out[16384 + 3 * 32 + m] = s3;
    }
}

extern "C" void kernel_launch(void* const* d_in, const int* in_sizes, int n_in,
                              void* d_out, int out_size, void* d_ws, size_t ws_size,
                              hipStream_t stream) {
    const float* x = (const float*)d_in[0];
    const int* ei = (const int*)d_in[1];
    const float* W1 = (const float*)d_in[2];
    const float* as1 = (const float*)d_in[3];
    const float* ad1 = (const float*)d_in[4];
    const float* b1 = (const float*)d_in[5];
    const float* W2 = (const float*)d_in[6];
    const float* as2 = (const float*)d_in[7];
    const float* ad2 = (const float*)d_in[8];
    const float* b2 = (const float*)d_in[9];
    const float* W3 = (const float*)d_in[10];
    const float* as3 = (const float*)d_in[11];
    const float* ad3 = (const float*)d_in[12];
    const float* b3 = (const float*)d_in[13];
    const float* Wih_f = (const float*)d_in[14];
    const float* Whh_f = (const float*)d_in[15];
    const float* bih_f = (const float*)d_in[16];
    const float* bhh_f = (const float*)d_in[17];
    const float* Wih_b = (const float*)d_in[18];
    const float* Whh_b = (const float*)d_in[19];
    const float* bih_b = (const float*)d_in[20];
    const float* bhh_b = (const float*)d_in[21];
    const float* Wmu = (const float*)d_in[22];
    const float* bmu = (const float*)d_in[23];
    const float* Wlv = (const float*)d_in[24];
    const float* blv = (const float*)d_in[25];
    const float* Wpi = (const float*)d_in[26];
    const float* bpi = (const float*)d_in[27];

    float* ws = (float*)d_ws;
    float* bufA = ws;                    // 4,194,304 f32 (feature buffer)
    float* bufB = ws + 4194304;          // 4,194,304 f32 (output buffer)
    float* asb = ws + 8388608;           // 65,536
    float* adb = ws + 8454144;           // 65,536
    int* cnt = (int*)(ws + 8519680);     // 128 ints
    int* col = cnt + 128;                // 32,768 ints
    float* gemb = ws + 8552576;          // 8,192
    float* xp = ws + 8560768;            // 262,144
    float* hT = ws + 8822912;            // 2,048 (final h per dir x batch)
    uint32_t* wg = (uint32_t*)ws;        // 65,536 u32 — overlaps bufA (dead by then)
    float* out = (float*)d_out;

    build_csr_kernel<<<1, 1024, 0, stream>>>(ei, cnt, col);

    // GAT layer 1
    gemm_kernel<<<dim3(4, 256), 256, 0, stream>>>(x, W1, bufA, NNODE, 256, 64);
    att_kernel<4><<<4096, 256, 0, stream>>>(bufA, as1, ad1, asb, adb);
    agg_kernel<4><<<4096, 256, 0, stream>>>(bufA, asb, adb, cnt, col, b1, bufB);
    // GAT layer 2
    gemm_kernel<<<dim3(4, 256), 256, 0, stream>>>(bufB, W2, bufA, NNODE, 256, 256);
    att_kernel<4><<<4096, 256, 0, stream>>>(bufA, as2, ad2, asb, adb);
    agg_kernel<4><<<4096, 256, 0, stream>>>(bufA, asb, adb, cnt, col, b2, bufB);
    // GAT layer 3 (single head)
    gemm_kernel<<<dim3(1, 256), 256, 0, stream>>>(bufB, W3, bufA, NNODE, 64, 256);
    att_kernel<1><<<4096, 256, 0, stream>>>(bufA, as3, ad3, asb, adb);
    agg_kernel<1><<<4096, 256, 0, stream>>>(bufA, asb, adb, cnt, col, b3, bufB);
    // bufA dead from here on -> wg may overwrite its first 256 KB
    wpack_kernel<<<8, 256, 0, stream>>>(Whh_f, Whh_b, wg);
    // pool + BiLSTM + heads
    pool_kernel<<<128, 64, 0, stream>>>(bufB, gemb);
    xpart_kernel<<<128, 256, 0, stream>>>(gemb, Wih_f, bih_f, bhh_f, Wih_b, bih_b, bhh_b, xp);
    lstm_kernel<<<8, 1024, 0, stream>>>(xp, Whh_f, Whh_b, wg, hT);
    heads_kernel<<<17, 256, 0, stream>>>(hT, Wmu, bmu, Wlv, blv, Wpi, bpi, out);
}

// Round 3
// 421.149 us; speedup vs baseline: 1.8147x; 1.6596x over previous
//
#include <hip/hip_runtime.h>
#include <hip/hip_bf16.h>
#include <cstdint>

#define NLOC 128        // nodes per graph
#define NGRAPH 128      // bs*T
#define NNODE 16384     // total nodes
#define EBASE 2048      // base edges per graph
#define CSTRIDE 256     // csr col stride per local node

typedef _Float16 half2v __attribute__((ext_vector_type(2)));

__device__ __forceinline__ float sigf(float x) { return 1.f / (1.f + __expf(-x)); }
__device__ __forceinline__ float tanhfast(float x) {
    float e = __expf(2.f * x);
    return 1.f - 2.f / (e + 1.f);
}
__device__ __forceinline__ uint32_t packh2(float a, float b) {
    half2v v;
    v.x = (_Float16)a; v.y = (_Float16)b;
    return __builtin_bit_cast(uint32_t, v);
}
__device__ __forceinline__ float dot2(uint32_t w, uint32_t h, float acc) {
#if __has_builtin(__builtin_amdgcn_fdot2)
    return __builtin_amdgcn_fdot2(__builtin_bit_cast(half2v, w),
                                  __builtin_bit_cast(half2v, h), acc, false);
#else
    half2v wv = __builtin_bit_cast(half2v, w);
    half2v hv = __builtin_bit_cast(half2v, h);
    return acc + (float)wv.x * (float)hv.x + (float)wv.y * (float)hv.y;
#endif
}

// ---------------- CSR of the shared per-graph edge list (dst -> list of src) ----------------
__global__ __launch_bounds__(1024) void build_csr_kernel(const int* __restrict__ ei,
                                                         int* __restrict__ cnt,
                                                         int* __restrict__ col) {
    __shared__ int c8[NLOC][8];
    int tid = threadIdx.x;
    int v = tid >> 3, p = tid & 7;
    const int* srcs = ei;
    const int* dsts = ei + EBASE;
    int e0 = p * 256, e1 = e0 + 256;
    int c = 0;
    for (int e = e0; e < e1; ++e) c += (dsts[e] == v);
    c8[v][p] = c;
    __syncthreads();
    int start = 0;
    for (int q = 0; q < p; ++q) start += c8[v][q];
    if (p == 0) {
        int tot = 0;
        for (int q = 0; q < 8; ++q) tot += c8[v][q];
        cnt[v] = tot;
    }
    int w = start;
    for (int e = e0; e < e1; ++e)
        if (dsts[e] == v) col[v * CSTRIDE + (w++)] = srcs[e];
}

// ---------------- fp32 tiled GEMM: C[M,N] = A[M,K] @ B[K,N]; M%64==0, N%64==0, K%16==0 ----
__global__ __launch_bounds__(256) void gemm_kernel(const float* __restrict__ A,
                                                   const float* __restrict__ B,
                                                   float* __restrict__ C,
                                                   int M, int N, int K) {
    __shared__ __align__(16) float As[16][64];
    __shared__ __align__(16) float Bs[16][64];
    int tid = threadIdx.x;
    int bm = blockIdx.y, bn = blockIdx.x;
    int am = tid >> 2, ak = (tid & 3) << 2;
    int bk = tid >> 4, bn4 = (tid & 15) << 2;
    int ty = tid >> 4, tx = tid & 15;
    const float* Ab = A + (size_t)bm * 64 * K;
    const float* Bb = B + bn * 64;
    float acc[4][4] = {};
    for (int k0 = 0; k0 < K; k0 += 16) {
        float4 av = *(const float4*)(Ab + (size_t)am * K + k0 + ak);
        float4 bv = *(const float4*)(Bb + (size_t)(k0 + bk) * N + bn4);
        As[ak + 0][am] = av.x; As[ak + 1][am] = av.y;
        As[ak + 2][am] = av.z; As[ak + 3][am] = av.w;
        *(float4*)&Bs[bk][bn4] = bv;
        __syncthreads();
#pragma unroll
        for (int kk = 0; kk < 16; ++kk) {
            float4 a4 = *(const float4*)&As[kk][ty << 2];
            float4 b4 = *(const float4*)&Bs[kk][tx << 2];
            acc[0][0] += a4.x * b4.x; acc[0][1] += a4.x * b4.y; acc[0][2] += a4.x * b4.z; acc[0][3] += a4.x * b4.w;
            acc[1][0] += a4.y * b4.x; acc[1][1] += a4.y * b4.y; acc[1][2] += a4.y * b4.z; acc[1][3] += a4.y * b4.w;
            acc[2][0] += a4.z * b4.x; acc[2][1] += a4.z * b4.y; acc[2][2] += a4.z * b4.z; acc[2][3] += a4.z * b4.w;
            acc[3][0] += a4.w * b4.x; acc[3][1] += a4.w * b4.y; acc[3][2] += a4.w * b4.z; acc[3][3] += a4.w * b4.w;
        }
        __syncthreads();
    }
    float* Cb = C + (size_t)(bm * 64 + ty * 4) * N + bn * 64 + tx * 4;
#pragma unroll
    for (int i = 0; i < 4; ++i)
        *(float4*)(Cb + (size_t)i * N) = make_float4(acc[i][0], acc[i][1], acc[i][2], acc[i][3]);
}

// ---------------- attention dot products per node ----------------
template <int H>
__global__ __launch_bounds__(256) void att_kernel(const float* __restrict__ hf,
                                                  const float* __restrict__ a_s,
                                                  const float* __restrict__ a_d,
                                                  float* __restrict__ asb,
                                                  float* __restrict__ adb) {
    int lane = threadIdx.x & 63;
    int n = blockIdx.x * 4 + (threadIdx.x >> 6);
    const float* row = hf + (size_t)n * (H * 64);
#pragma unroll
    for (int h = 0; h < H; ++h) {
        float v = row[h * 64 + lane];
        float ps = v * a_s[h * 64 + lane];
        float pd = v * a_d[h * 64 + lane];
#pragma unroll
        for (int off = 32; off > 0; off >>= 1) {
            ps += __shfl_xor(ps, off, 64);
            pd += __shfl_xor(pd, off, 64);
        }
        if (lane == 0) { asb[n * H + h] = ps; adb[n * H + h] = pd; }
    }
}

// ---------------- GAT aggregation: softmax over in-edges, gather, +bias, ReLU -------------
template <int H>
__global__ __launch_bounds__(256) void agg_kernel(const float* __restrict__ hf,
                                                  const float* __restrict__ asb,
                                                  const float* __restrict__ adb,
                                                  const int* __restrict__ cnt,
                                                  const int* __restrict__ col,
                                                  const float* __restrict__ bias,
                                                  float* __restrict__ out) {
    __shared__ float e_lds[4][96][H];
    __shared__ int u_lds[4][96];
    int lane = threadIdx.x & 63, w = threadIdx.x >> 6;
    int n = blockIdx.x * 4 + w;
    int v = n & 127, base = n & ~127;
    int deg = cnt[v];
    int tot = min(deg + 1, 96);
    float adst[H];
#pragma unroll
    for (int h = 0; h < H; ++h) adst[h] = adb[n * H + h];
    for (int k = lane; k < tot; k += 64) {
        int u = (k < deg) ? col[v * CSTRIDE + k] : v;
        u_lds[w][k] = u;
#pragma unroll
        for (int h = 0; h < H; ++h) {
            float e = asb[(base + u) * H + h] + adst[h];
            e_lds[w][k][h] = (e > 0.f) ? e : 0.2f * e;
        }
    }
    __syncthreads();
    float m[H];
#pragma unroll
    for (int h = 0; h < H; ++h) m[h] = -1e30f;
    for (int k = 0; k < tot; ++k)
#pragma unroll
        for (int h = 0; h < H; ++h) m[h] = fmaxf(m[h], e_lds[w][k][h]);
    __syncthreads();
    for (int k = lane; k < tot; k += 64)
#pragma unroll
        for (int h = 0; h < H; ++h) e_lds[w][k][h] = __expf(e_lds[w][k][h] - m[h]);
    __syncthreads();
    float den[H], acc[H];
#pragma unroll
    for (int h = 0; h < H; ++h) { den[h] = 0.f; acc[h] = 0.f; }
    for (int k = 0; k < tot; ++k) {
        int u = u_lds[w][k];
        const float* hr = hf + (size_t)(base + u) * (H * 64);
#pragma unroll
        for (int h = 0; h < H; ++h) {
            float wgt = e_lds[w][k][h];
            den[h] += wgt;
            acc[h] += wgt * hr[h * 64 + lane];
        }
    }
#pragma unroll
    for (int h = 0; h < H; ++h) {
        float o = acc[h] / (den[h] + 1e-16f) + bias[h * 64 + lane];
        out[(size_t)n * (H * 64) + h * 64 + lane] = fmaxf(o, 0.f);
    }
}

// ---------------- graph sum-pool into sequence layout [t*4+b][64] ----------------
__global__ void pool_kernel(const float* __restrict__ h, float* __restrict__ gemb) {
    int g = blockIdx.x;       // g = b*32 + t
    int c = threadIdx.x;      // 64 threads
    int b = g >> 5, t = g & 31;
    float s = 0.f;
    const float* p = h + (size_t)g * 128 * 64 + c;
    for (int vv = 0; vv < 128; ++vv) s += p[vv * 64];
    gemb[(t * 4 + b) * 64 + c] = s;
}

// ---------------- LSTM input part: xp[dir][r][o] = seq[r] . Wih[o] + bih[o] + bhh[o] ------
__global__ __launch_bounds__(256) void xpart_kernel(const float* __restrict__ gemb,
                                                    const float* __restrict__ Wf, const float* __restrict__ bif, const float* __restrict__ bhf,
                                                    const float* __restrict__ Wb, const float* __restrict__ bib, const float* __restrict__ bhb,
                                                    float* __restrict__ xp) {
    __shared__ float a[64];
    int r = blockIdx.x, tid = threadIdx.x;
    if (tid < 64) a[tid] = gemb[r * 64 + tid];
    __syncthreads();
    for (int dir = 0; dir < 2; ++dir) {
        const float* W = dir ? Wb : Wf;
        const float* bi = dir ? bib : bif;
        const float* bh = dir ? bhb : bhf;
        for (int o = tid; o < 1024; o += 256) {
            const float* wr = W + (size_t)o * 64;
            float s = bi[o] + bh[o];
#pragma unroll
            for (int k = 0; k < 64; k += 4) {
                float4 wv = *(const float4*)(wr + k);
                s += a[k] * wv.x + a[k + 1] * wv.y + a[k + 2] * wv.z + a[k + 3] * wv.w;
            }
            xp[dir * 131072 + r * 1024 + o] = s;
        }
    }
}

// ---------------- pre-pack Whh to f16 pairs: reg part [dir][chunk i][row] (uint4),
//                  tail part transposed [dir][ku][row] (u32) ----------------
__global__ __launch_bounds__(256) void wpack_kernel(const float* __restrict__ Whh_f,
                                                    const float* __restrict__ Whh_b,
                                                    uint32_t* __restrict__ wreg,
                                                    uint32_t* __restrict__ wtail) {
    int gid = blockIdx.x * 256 + threadIdx.x;   // 0..2047
    int dir = gid >> 10, row = gid & 1023;
    const float* src = (dir ? Whh_b : Whh_f) + (size_t)row * 256;
    // cols 0..191 -> 24 uint4 chunks (8 cols each), coalesced-by-row layout
    uint4* wr4 = (uint4*)wreg;
#pragma unroll
    for (int i = 0; i < 24; ++i) {
        uint4 v;
        v.x = packh2(src[i * 8 + 0], src[i * 8 + 1]);
        v.y = packh2(src[i * 8 + 2], src[i * 8 + 3]);
        v.z = packh2(src[i * 8 + 4], src[i * 8 + 5]);
        v.w = packh2(src[i * 8 + 6], src[i * 8 + 7]);
        wr4[(size_t)(dir * 24 + i) * 1024 + row] = v;
    }
    // cols 192..255 -> 32 u32, transposed [ku][row]
#pragma unroll
    for (int ku = 0; ku < 32; ++ku) {
        wtail[(size_t)(dir * 32 + ku) * 1024 + row] =
            packh2(src[192 + ku * 2], src[192 + ku * 2 + 1]);
    }
}

// ---------------- BiLSTM recurrent: 8 independent blocks (dir x batch) --------------------
// 512 threads, 2 gate-rows each (row, row+512); weights f16-packed: 192 cols in VGPRs,
// 64 cols in LDS (transposed, conflict-free b32); h as packed half2 broadcast from LDS.
__global__ __launch_bounds__(512, 2) void lstm_kernel(const float* __restrict__ xp,
                                                      const uint32_t* __restrict__ wreg,
                                                      const uint32_t* __restrict__ wtail,
                                                      float* __restrict__ hT) {
    int blk = blockIdx.x;
    int dir = blk >> 2, batch = blk & 3;
    int tid = threadIdx.x;                    // row_a = tid, row_b = tid + 512
    uint32_t wa[96], wb[96];
    {
        const uint4* ra = (const uint4*)wreg + (size_t)dir * 24 * 1024 + tid;
#pragma unroll
        for (int i = 0; i < 24; ++i) {
            uint4 v = ra[i * 1024];
            wa[i * 4 + 0] = v.x; wa[i * 4 + 1] = v.y; wa[i * 4 + 2] = v.z; wa[i * 4 + 3] = v.w;
        }
#pragma unroll
        for (int i = 0; i < 24; ++i) {
            uint4 v = ra[i * 1024 + 512];
            wb[i * 4 + 0] = v.x; wb[i * 4 + 1] = v.y; wb[i * 4 + 2] = v.z; wb[i * 4 + 3] = v.w;
        }
    }
    __shared__ uint32_t wlds[32 * 1024];      // 128 KB tail, [ku][row]
    __shared__ uint32_t h_pk[128];            // h as 128 half2 pairs
    __shared__ float gv[1024];
    {
        const uint32_t* tsrc = wtail + (size_t)dir * 32 * 1024;
        for (int i = tid; i < 32 * 1024; i += 512) wlds[i] = tsrc[i];
    }
    if (tid < 128) h_pk[tid] = 0;
    __syncthreads();
    float creg = 0.f;
    const float* xpb = xp + dir * 131072 + batch * 1024;
#pragma unroll 1
    for (int step = 0; step < 32; ++step) {
        int teff = dir ? (31 - step) : step;
        float xa = xpb[teff * 4096 + tid];
        float xb = xpb[teff * 4096 + tid + 512];
        float acca = 0.f, accb = 0.f;
#pragma unroll
        for (int q = 0; q < 24; ++q) {
            uint4 hq = *(const uint4*)&h_pk[q * 4];
            acca = dot2(wa[q * 4 + 0], hq.x, acca);
            acca = dot2(wa[q * 4 + 1], hq.y, acca);
            acca = dot2(wa[q * 4 + 2], hq.z, acca);
            acca = dot2(wa[q * 4 + 3], hq.w, acca);
            accb = dot2(wb[q * 4 + 0], hq.x, accb);
            accb = dot2(wb[q * 4 + 1], hq.y, accb);
            accb = dot2(wb[q * 4 + 2], hq.z, accb);
            accb = dot2(wb[q * 4 + 3], hq.w, accb);
        }
#pragma unroll
        for (int ku = 0; ku < 32; ++ku) {
            uint32_t hq = h_pk[96 + ku];
            acca = dot2(wlds[ku * 1024 + tid], hq, acca);
            accb = dot2(wlds[ku * 1024 + 512 + tid], hq, accb);
        }
        gv[tid] = acca + xa;
        gv[tid + 512] = accb + xb;
        __syncthreads();
        float hv = 0.f;
        if (tid < 256) {
            float iv = gv[tid], fv = gv[tid + 256], gg = gv[tid + 512], ov = gv[tid + 768];
            creg = sigf(fv) * creg + sigf(iv) * tanhfast(gg);
            hv = sigf(ov) * tanhfast(creg);
            if (step == 31) hT[(size_t)(dir * 4 + batch) * 256 + tid] = hv;
        }
        __syncthreads();   // gv reads done before h_pk overwrite (h_pk disjoint, but keep order vs next gv write)
        if (tid < 256) {
            float hnext = __shfl_down(hv, 1, 64);
            if ((tid & 1) == 0) h_pk[tid >> 1] = packh2(hv, hnext);
        }
        __syncthreads();
    }
}

// ---------------- heads: mu/logvar/pi from concat(h_f, h_b) ----------------
__global__ __launch_bounds__(256) void heads_kernel(const float* __restrict__ hT,
                                                    const float* __restrict__ Wmu, const float* __restrict__ bmu,
                                                    const float* __restrict__ Wlv, const float* __restrict__ blv,
                                                    const float* __restrict__ Wpi, const float* __restrict__ bpi,
                                                    float* __restrict__ out) {
    __shared__ __align__(16) float feat[4][512];
    int tid = threadIdx.x;
    for (int i = tid; i < 2048; i += 256) {
        int b = i >> 9, j = i & 511;
        int d = j >> 8, jj = j & 255;
        feat[b][j] = hT[(size_t)(d * 4 + b) * 256 + jj];
    }
    __syncthreads();
    int o = blockIdx.x * 256 + tid;
    if (o >= 4128) return;
    const float* Wr;
    float bv;
    int kind, m;
    if (o < 2048) { Wr = Wmu + (size_t)o * 512; bv = bmu[o]; kind = 0; m = o; }
    else if (o < 4096) { m = o - 2048; Wr = Wlv + (size_t)m * 512; bv = blv[m]; kind = 1; }
    else { m = o - 4096; Wr = Wpi + (size_t)m * 512; bv = bpi[m]; kind = 2; }
    float s0 = bv, s1 = bv, s2 = bv, s3 = bv;
    for (int k = 0; k < 512; k += 4) {
        float4 wv = *(const float4*)(Wr + k);
        s0 += feat[0][k] * wv.x + feat[0][k + 1] * wv.y + feat[0][k + 2] * wv.z + feat[0][k + 3] * wv.w;
        s1 += feat[1][k] * wv.x + feat[1][k + 1] * wv.y + feat[1][k + 2] * wv.z + feat[1][k + 3] * wv.w;
        s2 += feat[2][k] * wv.x + feat[2][k + 1] * wv.y + feat[2][k + 2] * wv.z + feat[2][k + 3] * wv.w;
        s3 += feat[3][k] * wv.x + feat[3][k + 1] * wv.y + feat[3][k + 2] * wv.z + feat[3][k + 3] * wv.w;
    }
    if (kind == 0) {
        out[0 * 2048 + m] = s0; out[1 * 2048 + m] = s1; out[2 * 2048 + m] = s2; out[3 * 2048 + m] = s3;
    } else if (kind == 1) {
        out[8192 + 0 * 2048 + m] = s0; out[8192 + 1 * 2048 + m] = s1;
        out[8192 + 2 * 2048 + m] = s2; out[8192 + 3 * 2048 + m] = s3;
    } else {
        out[16384 + 0 * 32 + m] = s0; out[16384 + 1 * 32 + m] = s1;
        out[16384 + 2 * 32 + m] = s2; out[16384 + 3 * 32 + m] = s3;
    }
}

extern "C" void kernel_launch(void* const* d_in, const int* in_sizes, int n_in,
                              void* d_out, int out_size, void* d_ws, size_t ws_size,
                              hipStream_t stream) {
    const float* x = (const float*)d_in[0];
    const int* ei = (const int*)d_in[1];
    const float* W1 = (const float*)d_in[2];
    const float* as1 = (const float*)d_in[3];
    const float* ad1 = (const float*)d_in[4];
    const float* b1 = (const float*)d_in[5];
    const float* W2 = (const float*)d_in[6];
    const float* as2 = (const float*)d_in[7];
    const float* ad2 = (const float*)d_in[8];
    const float* b2 = (const float*)d_in[9];
    const float* W3 = (const float*)d_in[10];
    const float* as3 = (const float*)d_in[11];
    const float* ad3 = (const float*)d_in[12];
    const float* b3 = (const float*)d_in[13];
    const float* Wih_f = (const float*)d_in[14];
    const float* Whh_f = (const float*)d_in[15];
    const float* bih_f = (const float*)d_in[16];
    const float* bhh_f = (const float*)d_in[17];
    const float* Wih_b = (const float*)d_in[18];
    const float* Whh_b = (const float*)d_in[19];
    const float* bih_b = (const float*)d_in[20];
    const float* bhh_b = (const float*)d_in[21];
    const float* Wmu = (const float*)d_in[22];
    const float* bmu = (const float*)d_in[23];
    const float* Wlv = (const float*)d_in[24];
    const float* blv = (const float*)d_in[25];
    const float* Wpi = (const float*)d_in[26];
    const float* bpi = (const float*)d_in[27];

    float* ws = (float*)d_ws;
    float* bufA = ws;                    // 4,194,304 f32 (feature buffer)
    float* bufB = ws + 4194304;          // 4,194,304 f32 (output buffer)
    float* asb = ws + 8388608;           // 65,536
    float* adb = ws + 8454144;           // 65,536
    int* cnt = (int*)(ws + 8519680);     // 128 ints
    int* col = cnt + 128;                // 32,768 ints
    float* gemb = ws + 8552576;          // 8,192
    float* xp = ws + 8560768;            // 262,144
    float* hT = ws + 8822912;            // 2,048 (final h per dir x batch)
    uint32_t* wreg = (uint32_t*)ws;      // 196,608 u32 — overlaps bufA (dead by then)
    uint32_t* wtail = wreg + 196608;     // 65,536 u32
    float* out = (float*)d_out;

    build_csr_kernel<<<1, 1024, 0, stream>>>(ei, cnt, col);

    // GAT layer 1
    gemm_kernel<<<dim3(4, 256), 256, 0, stream>>>(x, W1, bufA, NNODE, 256, 64);
    att_kernel<4><<<4096, 256, 0, stream>>>(bufA, as1, ad1, asb, adb);
    agg_kernel<4><<<4096, 256, 0, stream>>>(bufA, asb, adb, cnt, col, b1, bufB);
    // GAT layer 2
    gemm_kernel<<<dim3(4, 256), 256, 0, stream>>>(bufB, W2, bufA, NNODE, 256, 256);
    att_kernel<4><<<4096, 256, 0, stream>>>(bufA, as2, ad2, asb, adb);
    agg_kernel<4><<<4096, 256, 0, stream>>>(bufA, asb, adb, cnt, col, b2, bufB);
    // GAT layer 3 (single head)
    gemm_kernel<<<dim3(1, 256), 256, 0, stream>>>(bufB, W3, bufA, NNODE, 64, 256);
    att_kernel<1><<<4096, 256, 0, stream>>>(bufA, as3, ad3, asb, adb);
    agg_kernel<1><<<4096, 256, 0, stream>>>(bufA, asb, adb, cnt, col, b3, bufB);
    // bufA dead from here on -> wreg/wtail may overwrite its first 1 MB
    wpack_kernel<<<8, 256, 0, stream>>>(Whh_f, Whh_b, wreg, wtail);
    // pool + BiLSTM + heads
    pool_kernel<<<128, 64, 0, stream>>>(bufB, gemb);
    xpart_kernel<<<128, 256, 0, stream>>>(gemb, Wih_f, bih_f, bhh_f, Wih_b, bih_b, bhh_b, xp);
    lstm_kernel<<<8, 512, 0, stream>>>(xp, wreg, wtail, hT);
    heads_kernel<<<17, 256, 0, stream>>>(hT, Wmu, bmu, Wlv, blv, Wpi, bpi, out);
}